// Round 1
// baseline (523.166 us; speedup 1.0000x reference)
//
#include <hip/hip_runtime.h>

#define F 128

// ---------------- GRU weight evolution: W = GRUCell(W0, W0) ----------------
__global__ __launch_bounds__(128) void gru_evolve(
    const float* __restrict__ W0, const float* __restrict__ wih,
    const float* __restrict__ whh, const float* __restrict__ bih,
    const float* __restrict__ bhh, float* __restrict__ W) {
  __shared__ float w0row[F];
  int i = blockIdx.x, j = threadIdx.x;
  w0row[j] = W0[i * F + j];
  __syncthreads();
  float ar = 0, az = 0, an = 0, br = 0, bz = 0, bn = 0;
  const float* wi_r = wih + (size_t)j * F;
  const float* wi_z = wih + (size_t)(j + F) * F;
  const float* wi_n = wih + (size_t)(j + 2 * F) * F;
  const float* wh_r = whh + (size_t)j * F;
  const float* wh_z = whh + (size_t)(j + F) * F;
  const float* wh_n = whh + (size_t)(j + 2 * F) * F;
#pragma unroll 4
  for (int k = 0; k < F; ++k) {
    float a = w0row[k];
    ar = fmaf(a, wi_r[k], ar);
    az = fmaf(a, wi_z[k], az);
    an = fmaf(a, wi_n[k], an);
    br = fmaf(a, wh_r[k], br);
    bz = fmaf(a, wh_z[k], bz);
    bn = fmaf(a, wh_n[k], bn);
  }
  float gr = ar + bih[j] + br + bhh[j];
  float gz = az + bih[j + F] + bz + bhh[j + F];
  float r = 1.f / (1.f + expf(-gr));
  float z = 1.f / (1.f + expf(-gz));
  float n = tanhf(an + bih[j + 2 * F] + r * (bn + bhh[j + 2 * F]));
  W[i * F + j] = (1.f - z) * n + z * w0row[j];
}

// ---------------- degree + count histogram over edges ----------------
__global__ __launch_bounds__(256) void hist_kernel(
    const int* __restrict__ col, const float* __restrict__ ew,
    float* __restrict__ deg, int* __restrict__ cnt, int E) {
  int e = blockIdx.x * 256 + threadIdx.x;
  if (e < E) {
    int c = col[e];
    atomicAdd(&deg[c], ew[e]);
    atomicAdd(&cnt[c], 1);
  }
}

// ---------------- dinv = rsqrt(deg + 1)  (self-loop weight 1) ----------------
__global__ __launch_bounds__(256) void dinv_kernel(
    const float* __restrict__ deg, float* __restrict__ dinv, int N) {
  int i = blockIdx.x * 256 + threadIdx.x;
  if (i < N) dinv[i] = rsqrtf(deg[i] + 1.0f);
}

// ---------------- exclusive scan of cnt -> offsets (3-phase) ----------------
__global__ __launch_bounds__(1024) void scan_block(
    const int* __restrict__ cnt, int* __restrict__ offs, int* __restrict__ bsum, int N) {
  __shared__ int s[1024];
  int t = threadIdx.x;
  int idx = blockIdx.x * 1024 + t;
  int v = (idx < N) ? cnt[idx] : 0;
  s[t] = v;
  __syncthreads();
  for (int off = 1; off < 1024; off <<= 1) {
    int xv = (t >= off) ? s[t - off] : 0;
    __syncthreads();
    s[t] += xv;
    __syncthreads();
  }
  if (idx < N) offs[idx] = s[t] - v;  // exclusive within block
  if (t == 1023) bsum[blockIdx.x] = s[1023];
}

__global__ void scan_sums(const int* __restrict__ bsum, int* __restrict__ bscan,
                          int NB, int* __restrict__ offs, int N) {
  if (threadIdx.x == 0 && blockIdx.x == 0) {
    int run = 0;
    for (int b = 0; b < NB; ++b) {
      bscan[b] = run;
      run += bsum[b];
    }
    offs[N] = run;
  }
}

__global__ __launch_bounds__(256) void add_offsets(
    int* __restrict__ offs, const int* __restrict__ bscan, int* __restrict__ cursor, int N) {
  int i = blockIdx.x * 256 + threadIdx.x;
  if (i < N) {
    int v = offs[i] + bscan[i >> 10];
    offs[i] = v;
    cursor[i] = v;
  }
}

// ---------------- CSR fill: bucket (row, norm) by target col ----------------
__global__ __launch_bounds__(256) void fill_kernel(
    const int* __restrict__ row, const int* __restrict__ col,
    const float* __restrict__ ew, const float* __restrict__ dinv,
    int* __restrict__ cursor, uint2* __restrict__ pairs, int E) {
  int e = blockIdx.x * 256 + threadIdx.x;
  if (e < E) {
    int r = row[e], c = col[e];
    float nrm = dinv[r] * ew[e] * dinv[c];
    int p = atomicAdd(&cursor[c], 1);
    pairs[p] = make_uint2((unsigned)r, __float_as_uint(nrm));
  }
}

// ---------------- xw = x @ W  (fp32, W staged in LDS) ----------------
// block = 256 threads, tile = 128 rows x 128 cols, thread tile = 8x8
__global__ __launch_bounds__(256) void gemm_xw(
    const float* __restrict__ x, const float* __restrict__ W,
    float* __restrict__ xw, int N) {
  __shared__ float Ws[F * F];  // 64 KB -> 2 blocks/CU
  int t = threadIdx.x;
  for (int idx = t; idx < F * F; idx += 256) Ws[idx] = W[idx];
  __syncthreads();

  int tj = t & 15;        // 16 col-groups * 8 cols
  int ti = t >> 4;        // 16 row-groups * 8 rows
  int j0 = tj * 8;
  int i0 = blockIdx.x * 128 + ti * 8;

  const float* xp[8];
#pragma unroll
  for (int u = 0; u < 8; ++u) {
    int r = i0 + u;
    if (r > N - 1) r = N - 1;  // clamp for safe loads; stores are guarded
    xp[u] = x + (size_t)r * F;
  }

  float acc[8][8];
#pragma unroll
  for (int u = 0; u < 8; ++u)
#pragma unroll
    for (int v = 0; v < 8; ++v) acc[u][v] = 0.f;

  for (int k4 = 0; k4 < F / 4; ++k4) {
    float4 xv[8];
#pragma unroll
    for (int u = 0; u < 8; ++u) xv[u] = *(const float4*)(xp[u] + k4 * 4);
#pragma unroll
    for (int kk = 0; kk < 4; ++kk) {
      int k = k4 * 4 + kk;
      float4 wa = *(const float4*)&Ws[k * F + j0];
      float4 wb = *(const float4*)&Ws[k * F + j0 + 4];
#pragma unroll
      for (int u = 0; u < 8; ++u) {
        float xs = (kk == 0) ? xv[u].x : (kk == 1) ? xv[u].y : (kk == 2) ? xv[u].z : xv[u].w;
        acc[u][0] = fmaf(xs, wa.x, acc[u][0]);
        acc[u][1] = fmaf(xs, wa.y, acc[u][1]);
        acc[u][2] = fmaf(xs, wa.z, acc[u][2]);
        acc[u][3] = fmaf(xs, wa.w, acc[u][3]);
        acc[u][4] = fmaf(xs, wb.x, acc[u][4]);
        acc[u][5] = fmaf(xs, wb.y, acc[u][5]);
        acc[u][6] = fmaf(xs, wb.z, acc[u][6]);
        acc[u][7] = fmaf(xs, wb.w, acc[u][7]);
      }
    }
  }

#pragma unroll
  for (int u = 0; u < 8; ++u) {
    int r = i0 + u;
    if (r < N) {
      float4* dst = (float4*)(xw + (size_t)r * F + j0);
      dst[0] = make_float4(acc[u][0], acc[u][1], acc[u][2], acc[u][3]);
      dst[1] = make_float4(acc[u][4], acc[u][5], acc[u][6], acc[u][7]);
    }
  }
}

// ------------- fused gather + ReLU + Linear(F,1): out[i] -------------
// one wave per node; lanes split: half-wave h in {0,1} processes edges
// it = start+h, start+h+2, ...; each half-lane c in 0..31 owns 4 features.
__global__ __launch_bounds__(256) void gather_out(
    const uint2* __restrict__ pairs, const int* __restrict__ offs,
    const float* __restrict__ dinv, const float* __restrict__ xw,
    const float* __restrict__ linw, const float* __restrict__ linb,
    float* __restrict__ out, int N) {
  int wave = threadIdx.x >> 6;
  int lane = threadIdx.x & 63;
  int node = blockIdx.x * 4 + wave;
  if (node >= N) return;
  int c = lane & 31;
  int h = lane >> 5;

  const float4* xwv = (const float4*)xw;  // row i -> xwv[i*32 + c]
  float4 acc = make_float4(0.f, 0.f, 0.f, 0.f);

  if (h == 0) {  // self-loop, counted once
    float d = dinv[node];
    float s = d * d;
    float4 xv = xwv[(size_t)node * 32 + c];
    acc.x = s * xv.x; acc.y = s * xv.y; acc.z = s * xv.z; acc.w = s * xv.w;
  }

  int start = offs[node], end = offs[node + 1];
  int it = start + h;
  for (; it + 2 < end; it += 4) {  // 2 edges per half-wave in flight
    uint2 p0 = pairs[it];
    uint2 p1 = pairs[it + 2];
    float4 x0 = xwv[(size_t)p0.x * 32 + c];
    float4 x1 = xwv[(size_t)p1.x * 32 + c];
    float n0 = __uint_as_float(p0.y);
    float n1 = __uint_as_float(p1.y);
    acc.x = fmaf(n0, x0.x, acc.x); acc.y = fmaf(n0, x0.y, acc.y);
    acc.z = fmaf(n0, x0.z, acc.z); acc.w = fmaf(n0, x0.w, acc.w);
    acc.x = fmaf(n1, x1.x, acc.x); acc.y = fmaf(n1, x1.y, acc.y);
    acc.z = fmaf(n1, x1.z, acc.z); acc.w = fmaf(n1, x1.w, acc.w);
  }
  if (it < end) {
    uint2 p0 = pairs[it];
    float4 x0 = xwv[(size_t)p0.x * 32 + c];
    float n0 = __uint_as_float(p0.y);
    acc.x = fmaf(n0, x0.x, acc.x); acc.y = fmaf(n0, x0.y, acc.y);
    acc.z = fmaf(n0, x0.z, acc.z); acc.w = fmaf(n0, x0.w, acc.w);
  }

  // combine the two halves (each lane then holds the full sum for its 4 feats)
  acc.x += __shfl_xor(acc.x, 32);
  acc.y += __shfl_xor(acc.y, 32);
  acc.z += __shfl_xor(acc.z, 32);
  acc.w += __shfl_xor(acc.w, 32);

  // ReLU + dot with lin_w
  float4 lw = ((const float4*)linw)[c];
  float p = fmaxf(acc.x, 0.f) * lw.x + fmaxf(acc.y, 0.f) * lw.y +
            fmaxf(acc.z, 0.f) * lw.z + fmaxf(acc.w, 0.f) * lw.w;
#pragma unroll
  for (int m = 16; m; m >>= 1) p += __shfl_xor(p, m);

  if (lane == 0) out[node] = p + linb[0];
}

extern "C" void kernel_launch(void* const* d_in, const int* in_sizes, int n_in,
                              void* d_out, int out_size, void* d_ws, size_t ws_size,
                              hipStream_t stream) {
  const float* x    = (const float*)d_in[0];
  const int*   ei   = (const int*)d_in[1];
  const float* ew   = (const float*)d_in[2];
  const float* W0   = (const float*)d_in[3];
  const float* wih  = (const float*)d_in[4];
  const float* whh  = (const float*)d_in[5];
  const float* bih  = (const float*)d_in[6];
  const float* bhh  = (const float*)d_in[7];
  const float* linw = (const float*)d_in[8];
  const float* linb = (const float*)d_in[9];

  int N = in_sizes[0] / F;
  int E = in_sizes[2];
  const int* row = ei;
  const int* col = ei + E;

  // workspace carve-up (aligned to 256 B)
  char* p = (char*)d_ws;
  auto alloc = [&](size_t bytes) {
    char* q = p;
    p += (bytes + 255) & ~(size_t)255;
    return q;
  };
  float* W      = (float*)alloc((size_t)F * F * 4);
  float* deg    = (float*)alloc((size_t)N * 4);
  int*   cnt    = (int*)alloc((size_t)N * 4);
  float* dinv   = (float*)alloc((size_t)N * 4);
  int*   offs   = (int*)alloc(((size_t)N + 1) * 4);
  int*   cursor = (int*)alloc((size_t)N * 4);
  int*   bsum   = (int*)alloc(4096);
  int*   bscan  = (int*)alloc(4096);
  uint2* pairs  = (uint2*)alloc((size_t)E * 8);
  float* xw     = (float*)alloc((size_t)N * F * 4);

  hipMemsetAsync(deg, 0, (size_t)N * 4, stream);
  hipMemsetAsync(cnt, 0, (size_t)N * 4, stream);

  gru_evolve<<<F, F, 0, stream>>>(W0, wih, whh, bih, bhh, W);
  hist_kernel<<<(E + 255) / 256, 256, 0, stream>>>(col, ew, deg, cnt, E);
  dinv_kernel<<<(N + 255) / 256, 256, 0, stream>>>(deg, dinv, N);

  int NB = (N + 1023) / 1024;
  scan_block<<<NB, 1024, 0, stream>>>(cnt, offs, bsum, N);
  scan_sums<<<1, 64, 0, stream>>>(bsum, bscan, NB, offs, N);
  add_offsets<<<(N + 255) / 256, 256, 0, stream>>>(offs, bscan, cursor, N);

  fill_kernel<<<(E + 255) / 256, 256, 0, stream>>>(row, col, ew, dinv, cursor, pairs, E);
  gemm_xw<<<(N + 127) / 128, 256, 0, stream>>>(x, W, xw, N);
  gather_out<<<(N + 3) / 4, 256, 0, stream>>>(pairs, offs, dinv, xw, linw, linb,
                                              (float*)d_out, N);
}

// Round 2
// 410.454 us; speedup vs baseline: 1.2746x; 1.2746x over previous
//
#include <hip/hip_runtime.h>

#define F 128
#define DEG_SCALE 16777216.0f      // 2^24 fixed point for edge-weight sums
#define DEG_INV   (1.0f / 16777216.0f)

// ---------------- GRU weight evolution: W = GRUCell(W0, W0) ----------------
__global__ __launch_bounds__(128) void gru_evolve(
    const float* __restrict__ W0, const float* __restrict__ wih,
    const float* __restrict__ whh, const float* __restrict__ bih,
    const float* __restrict__ bhh, float* __restrict__ W) {
  __shared__ float w0row[F];
  int i = blockIdx.x, j = threadIdx.x;
  w0row[j] = W0[i * F + j];
  __syncthreads();
  float ar = 0, az = 0, an = 0, br = 0, bz = 0, bn = 0;
  const float* wi_r = wih + (size_t)j * F;
  const float* wi_z = wih + (size_t)(j + F) * F;
  const float* wi_n = wih + (size_t)(j + 2 * F) * F;
  const float* wh_r = whh + (size_t)j * F;
  const float* wh_z = whh + (size_t)(j + F) * F;
  const float* wh_n = whh + (size_t)(j + 2 * F) * F;
#pragma unroll 4
  for (int k = 0; k < F; ++k) {
    float a = w0row[k];
    ar = fmaf(a, wi_r[k], ar);
    az = fmaf(a, wi_z[k], az);
    an = fmaf(a, wi_n[k], an);
    br = fmaf(a, wh_r[k], br);
    bz = fmaf(a, wh_z[k], bz);
    bn = fmaf(a, wh_n[k], bn);
  }
  float gr = ar + bih[j] + br + bhh[j];
  float gz = az + bih[j + F] + bz + bhh[j + F];
  float r = 1.f / (1.f + expf(-gr));
  float z = 1.f / (1.f + expf(-gz));
  float n = tanhf(an + bih[j + 2 * F] + r * (bn + bhh[j + 2 * F]));
  W[i * F + j] = (1.f - z) * n + z * w0row[j];
}

// ------- single packed atomic per edge: hi32 = count, lo32 = fixed deg -------
// returned old hi32 is this edge's rank within its target bucket.
__global__ __launch_bounds__(256) void hist_packed(
    const int* __restrict__ col, const float* __restrict__ ew,
    unsigned long long* __restrict__ packed, unsigned* __restrict__ rank, int E) {
  int e = blockIdx.x * 256 + threadIdx.x;
  if (e < E) {
    int c = col[e];
    unsigned fx = (unsigned)(ew[e] * DEG_SCALE);
    unsigned long long old =
        atomicAdd(&packed[c], ((unsigned long long)1 << 32) | (unsigned long long)fx);
    rank[e] = (unsigned)(old >> 32);
  }
}

// ---------------- exclusive scan of counts -> offsets (3-phase) ----------------
__global__ __launch_bounds__(1024) void scan_block(
    const unsigned long long* __restrict__ packed, int* __restrict__ offs,
    int* __restrict__ bsum, int N) {
  __shared__ int s[1024];
  int t = threadIdx.x;
  int idx = blockIdx.x * 1024 + t;
  int v = (idx < N) ? (int)(packed[idx] >> 32) : 0;
  s[t] = v;
  __syncthreads();
  for (int off = 1; off < 1024; off <<= 1) {
    int xv = (t >= off) ? s[t - off] : 0;
    __syncthreads();
    s[t] += xv;
    __syncthreads();
  }
  if (idx < N) offs[idx] = s[t] - v;  // exclusive within block
  if (t == 1023) bsum[blockIdx.x] = s[1023];
}

__global__ void scan_sums(const int* __restrict__ bsum, int* __restrict__ bscan,
                          int NB, int* __restrict__ offs, int N) {
  if (threadIdx.x == 0 && blockIdx.x == 0) {
    int run = 0;
    for (int b = 0; b < NB; ++b) {
      bscan[b] = run;
      run += bsum[b];
    }
    offs[N] = run;
  }
}

// ---- finalize: offs += block prefix; dinv = rsqrt(deg + 1) (self loop) ----
__global__ __launch_bounds__(256) void finalize_kernel(
    int* __restrict__ offs, const int* __restrict__ bscan,
    const unsigned long long* __restrict__ packed, float* __restrict__ dinv, int N) {
  int i = blockIdx.x * 256 + threadIdx.x;
  if (i < N) {
    offs[i] += bscan[i >> 10];
    float deg = (float)(unsigned)(packed[i] & 0xffffffffull) * DEG_INV;
    dinv[i] = rsqrtf(deg + 1.0f);
  }
}

// ------------- CSR fill, atomic-free: p = offs[col] + rank[e] -------------
__global__ __launch_bounds__(256) void fill_kernel(
    const int* __restrict__ row, const int* __restrict__ col,
    const float* __restrict__ ew, const unsigned* __restrict__ rank,
    const int* __restrict__ offs, const float* __restrict__ dinv,
    uint2* __restrict__ pairs, int E) {
  int e = blockIdx.x * 256 + threadIdx.x;
  if (e < E) {
    int r = row[e], c = col[e];
    float nrm = dinv[r] * ew[e] * dinv[c];
    int p = offs[c] + (int)rank[e];
    pairs[p] = make_uint2((unsigned)r, __float_as_uint(nrm));
  }
}

// ---------------- xw = x @ W  (fp32, W staged in LDS) ----------------
__global__ __launch_bounds__(256) void gemm_xw(
    const float* __restrict__ x, const float* __restrict__ W,
    float* __restrict__ xw, int N) {
  __shared__ float Ws[F * F];  // 64 KB
  int t = threadIdx.x;
  for (int idx = t; idx < F * F; idx += 256) Ws[idx] = W[idx];
  __syncthreads();

  int tj = t & 15;
  int ti = t >> 4;
  int j0 = tj * 8;
  int i0 = blockIdx.x * 128 + ti * 8;

  const float* xp[8];
#pragma unroll
  for (int u = 0; u < 8; ++u) {
    int r = i0 + u;
    if (r > N - 1) r = N - 1;
    xp[u] = x + (size_t)r * F;
  }

  float acc[8][8];
#pragma unroll
  for (int u = 0; u < 8; ++u)
#pragma unroll
    for (int v = 0; v < 8; ++v) acc[u][v] = 0.f;

  for (int k4 = 0; k4 < F / 4; ++k4) {
    float4 xv[8];
#pragma unroll
    for (int u = 0; u < 8; ++u) xv[u] = *(const float4*)(xp[u] + k4 * 4);
#pragma unroll
    for (int kk = 0; kk < 4; ++kk) {
      int k = k4 * 4 + kk;
      float4 wa = *(const float4*)&Ws[k * F + j0];
      float4 wb = *(const float4*)&Ws[k * F + j0 + 4];
#pragma unroll
      for (int u = 0; u < 8; ++u) {
        float xs = (kk == 0) ? xv[u].x : (kk == 1) ? xv[u].y : (kk == 2) ? xv[u].z : xv[u].w;
        acc[u][0] = fmaf(xs, wa.x, acc[u][0]);
        acc[u][1] = fmaf(xs, wa.y, acc[u][1]);
        acc[u][2] = fmaf(xs, wa.z, acc[u][2]);
        acc[u][3] = fmaf(xs, wa.w, acc[u][3]);
        acc[u][4] = fmaf(xs, wb.x, acc[u][4]);
        acc[u][5] = fmaf(xs, wb.y, acc[u][5]);
        acc[u][6] = fmaf(xs, wb.z, acc[u][6]);
        acc[u][7] = fmaf(xs, wb.w, acc[u][7]);
      }
    }
  }

#pragma unroll
  for (int u = 0; u < 8; ++u) {
    int r = i0 + u;
    if (r < N) {
      float4* dst = (float4*)(xw + (size_t)r * F + j0);
      dst[0] = make_float4(acc[u][0], acc[u][1], acc[u][2], acc[u][3]);
      dst[1] = make_float4(acc[u][4], acc[u][5], acc[u][6], acc[u][7]);
    }
  }
}

// ------------- fused gather + ReLU + Linear(F,1): out[i] -------------
__global__ __launch_bounds__(256) void gather_out(
    const uint2* __restrict__ pairs, const int* __restrict__ offs,
    const float* __restrict__ dinv, const float* __restrict__ xw,
    const float* __restrict__ linw, const float* __restrict__ linb,
    float* __restrict__ out, int N) {
  int wave = threadIdx.x >> 6;
  int lane = threadIdx.x & 63;
  int node = blockIdx.x * 4 + wave;
  if (node >= N) return;
  int c = lane & 31;
  int h = lane >> 5;

  const float4* xwv = (const float4*)xw;
  float4 acc = make_float4(0.f, 0.f, 0.f, 0.f);

  if (h == 0) {  // self-loop
    float d = dinv[node];
    float s = d * d;
    float4 xv = xwv[(size_t)node * 32 + c];
    acc.x = s * xv.x; acc.y = s * xv.y; acc.z = s * xv.z; acc.w = s * xv.w;
  }

  int start = offs[node], end = offs[node + 1];
  int it = start + h;
  for (; it + 2 < end; it += 4) {
    uint2 p0 = pairs[it];
    uint2 p1 = pairs[it + 2];
    float4 x0 = xwv[(size_t)p0.x * 32 + c];
    float4 x1 = xwv[(size_t)p1.x * 32 + c];
    float n0 = __uint_as_float(p0.y);
    float n1 = __uint_as_float(p1.y);
    acc.x = fmaf(n0, x0.x, acc.x); acc.y = fmaf(n0, x0.y, acc.y);
    acc.z = fmaf(n0, x0.z, acc.z); acc.w = fmaf(n0, x0.w, acc.w);
    acc.x = fmaf(n1, x1.x, acc.x); acc.y = fmaf(n1, x1.y, acc.y);
    acc.z = fmaf(n1, x1.z, acc.z); acc.w = fmaf(n1, x1.w, acc.w);
  }
  if (it < end) {
    uint2 p0 = pairs[it];
    float4 x0 = xwv[(size_t)p0.x * 32 + c];
    float n0 = __uint_as_float(p0.y);
    acc.x = fmaf(n0, x0.x, acc.x); acc.y = fmaf(n0, x0.y, acc.y);
    acc.z = fmaf(n0, x0.z, acc.z); acc.w = fmaf(n0, x0.w, acc.w);
  }

  acc.x += __shfl_xor(acc.x, 32);
  acc.y += __shfl_xor(acc.y, 32);
  acc.z += __shfl_xor(acc.z, 32);
  acc.w += __shfl_xor(acc.w, 32);

  float4 lw = ((const float4*)linw)[c];
  float p = fmaxf(acc.x, 0.f) * lw.x + fmaxf(acc.y, 0.f) * lw.y +
            fmaxf(acc.z, 0.f) * lw.z + fmaxf(acc.w, 0.f) * lw.w;
#pragma unroll
  for (int m = 16; m; m >>= 1) p += __shfl_xor(p, m);

  if (lane == 0) out[node] = p + linb[0];
}

extern "C" void kernel_launch(void* const* d_in, const int* in_sizes, int n_in,
                              void* d_out, int out_size, void* d_ws, size_t ws_size,
                              hipStream_t stream) {
  const float* x    = (const float*)d_in[0];
  const int*   ei   = (const int*)d_in[1];
  const float* ew   = (const float*)d_in[2];
  const float* W0   = (const float*)d_in[3];
  const float* wih  = (const float*)d_in[4];
  const float* whh  = (const float*)d_in[5];
  const float* bih  = (const float*)d_in[6];
  const float* bhh  = (const float*)d_in[7];
  const float* linw = (const float*)d_in[8];
  const float* linb = (const float*)d_in[9];

  int N = in_sizes[0] / F;
  int E = in_sizes[2];
  const int* row = ei;
  const int* col = ei + E;

  char* p = (char*)d_ws;
  auto alloc = [&](size_t bytes) {
    char* q = p;
    p += (bytes + 255) & ~(size_t)255;
    return q;
  };
  float*              W      = (float*)alloc((size_t)F * F * 4);
  unsigned long long* packed = (unsigned long long*)alloc((size_t)N * 8);
  unsigned*           rank   = (unsigned*)alloc((size_t)E * 4);
  float*              dinv   = (float*)alloc((size_t)N * 4);
  int*                offs   = (int*)alloc(((size_t)N + 1) * 4);
  int*                bsum   = (int*)alloc(4096);
  int*                bscan  = (int*)alloc(4096);
  uint2*              pairs  = (uint2*)alloc((size_t)E * 8);
  float*              xw     = (float*)alloc((size_t)N * F * 4);

  hipMemsetAsync(packed, 0, (size_t)N * 8, stream);

  gru_evolve<<<F, F, 0, stream>>>(W0, wih, whh, bih, bhh, W);
  hist_packed<<<(E + 255) / 256, 256, 0, stream>>>(col, ew, packed, rank, E);

  int NB = (N + 1023) / 1024;
  scan_block<<<NB, 1024, 0, stream>>>(packed, offs, bsum, N);
  scan_sums<<<1, 64, 0, stream>>>(bsum, bscan, NB, offs, N);
  finalize_kernel<<<(N + 255) / 256, 256, 0, stream>>>(offs, bscan, packed, dinv, N);

  fill_kernel<<<(E + 255) / 256, 256, 0, stream>>>(row, col, ew, rank, offs, dinv, pairs, E);
  gemm_xw<<<(N + 127) / 128, 256, 0, stream>>>(x, W, xw, N);
  gather_out<<<(N + 3) / 4, 256, 0, stream>>>(pairs, offs, dinv, xw, linw, linb,
                                              (float*)d_out, N);
}

// Round 3
// 348.861 us; speedup vs baseline: 1.4996x; 1.1766x over previous
//
#include <hip/hip_runtime.h>

#define F 128
#define DEG_SCALE 16777216.0f      // 2^24 fixed point for edge-weight sums
#define DEG_INV   (1.0f / 16777216.0f)

typedef _Float16 half8 __attribute__((ext_vector_type(8)));

// ---------------- GRU weight evolution: W = GRUCell(W0, W0) ----------------
__global__ __launch_bounds__(128) void gru_evolve(
    const float* __restrict__ W0, const float* __restrict__ wih,
    const float* __restrict__ whh, const float* __restrict__ bih,
    const float* __restrict__ bhh, float* __restrict__ W) {
  __shared__ float w0row[F];
  int i = blockIdx.x, j = threadIdx.x;
  w0row[j] = W0[i * F + j];
  __syncthreads();
  float ar = 0, az = 0, an = 0, br = 0, bz = 0, bn = 0;
  const float* wi_r = wih + (size_t)j * F;
  const float* wi_z = wih + (size_t)(j + F) * F;
  const float* wi_n = wih + (size_t)(j + 2 * F) * F;
  const float* wh_r = whh + (size_t)j * F;
  const float* wh_z = whh + (size_t)(j + F) * F;
  const float* wh_n = whh + (size_t)(j + 2 * F) * F;
#pragma unroll 4
  for (int k = 0; k < F; ++k) {
    float a = w0row[k];
    ar = fmaf(a, wi_r[k], ar);
    az = fmaf(a, wi_z[k], az);
    an = fmaf(a, wi_n[k], an);
    br = fmaf(a, wh_r[k], br);
    bz = fmaf(a, wh_z[k], bz);
    bn = fmaf(a, wh_n[k], bn);
  }
  float gr = ar + bih[j] + br + bhh[j];
  float gz = az + bih[j + F] + bz + bhh[j + F];
  float r = 1.f / (1.f + expf(-gr));
  float z = 1.f / (1.f + expf(-gz));
  float n = tanhf(an + bih[j + 2 * F] + r * (bn + bhh[j + 2 * F]));
  W[i * F + j] = (1.f - z) * n + z * w0row[j];
}

// ------- single packed atomic per edge: hi32 = count, lo32 = fixed deg -------
__global__ __launch_bounds__(256) void hist_packed(
    const int* __restrict__ col, const float* __restrict__ ew,
    unsigned long long* __restrict__ packed, unsigned* __restrict__ rank, int E) {
  int e = blockIdx.x * 256 + threadIdx.x;
  if (e < E) {
    int c = col[e];
    unsigned fx = (unsigned)(ew[e] * DEG_SCALE);
    unsigned long long old =
        atomicAdd(&packed[c], ((unsigned long long)1 << 32) | (unsigned long long)fx);
    rank[e] = (unsigned)(old >> 32);
  }
}

// ---------------- exclusive scan of counts -> offsets (3-phase) ----------------
__global__ __launch_bounds__(1024) void scan_block(
    const unsigned long long* __restrict__ packed, int* __restrict__ offs,
    int* __restrict__ bsum, int N) {
  __shared__ int s[1024];
  int t = threadIdx.x;
  int idx = blockIdx.x * 1024 + t;
  int v = (idx < N) ? (int)(packed[idx] >> 32) : 0;
  s[t] = v;
  __syncthreads();
  for (int off = 1; off < 1024; off <<= 1) {
    int xv = (t >= off) ? s[t - off] : 0;
    __syncthreads();
    s[t] += xv;
    __syncthreads();
  }
  if (idx < N) offs[idx] = s[t] - v;
  if (t == 1023) bsum[blockIdx.x] = s[1023];
}

__global__ void scan_sums(const int* __restrict__ bsum, int* __restrict__ bscan,
                          int NB, int* __restrict__ offs, int N) {
  if (threadIdx.x == 0 && blockIdx.x == 0) {
    int run = 0;
    for (int b = 0; b < NB; ++b) {
      bscan[b] = run;
      run += bsum[b];
    }
    offs[N] = run;
  }
}

// ---- finalize: offs += block prefix; dinv = rsqrt(deg + 1) (self loop) ----
__global__ __launch_bounds__(256) void finalize_kernel(
    int* __restrict__ offs, const int* __restrict__ bscan,
    const unsigned long long* __restrict__ packed, float* __restrict__ dinv, int N) {
  int i = blockIdx.x * 256 + threadIdx.x;
  if (i < N) {
    offs[i] += bscan[i >> 10];
    float deg = (float)(unsigned)(packed[i] & 0xffffffffull) * DEG_INV;
    dinv[i] = rsqrtf(deg + 1.0f);
  }
}

// ------------- CSR fill, atomic-free: p = offs[col] + rank[e] -------------
__global__ __launch_bounds__(256) void fill_kernel(
    const int* __restrict__ row, const int* __restrict__ col,
    const float* __restrict__ ew, const unsigned* __restrict__ rank,
    const int* __restrict__ offs, const float* __restrict__ dinv,
    uint2* __restrict__ pairs, int E) {
  int e = blockIdx.x * 256 + threadIdx.x;
  if (e < E) {
    int r = row[e], c = col[e];
    float nrm = dinv[r] * ew[e] * dinv[c];
    int p = offs[c] + (int)rank[e];
    pairs[p] = make_uint2((unsigned)r, __float_as_uint(nrm));
  }
}

// ------------- xw = x @ W  (fp32 accum, fp16 output, W staged in LDS) -------------
__global__ __launch_bounds__(256) void gemm_xw(
    const float* __restrict__ x, const float* __restrict__ W,
    _Float16* __restrict__ xwh, int N) {
  __shared__ float Ws[F * F];  // 64 KB
  int t = threadIdx.x;
  for (int idx = t; idx < F * F; idx += 256) Ws[idx] = W[idx];
  __syncthreads();

  int tj = t & 15;
  int ti = t >> 4;
  int j0 = tj * 8;
  int i0 = blockIdx.x * 128 + ti * 8;

  const float* xp[8];
#pragma unroll
  for (int u = 0; u < 8; ++u) {
    int r = i0 + u;
    if (r > N - 1) r = N - 1;
    xp[u] = x + (size_t)r * F;
  }

  float acc[8][8];
#pragma unroll
  for (int u = 0; u < 8; ++u)
#pragma unroll
    for (int v = 0; v < 8; ++v) acc[u][v] = 0.f;

  for (int k4 = 0; k4 < F / 4; ++k4) {
    float4 xv[8];
#pragma unroll
    for (int u = 0; u < 8; ++u) xv[u] = *(const float4*)(xp[u] + k4 * 4);
#pragma unroll
    for (int kk = 0; kk < 4; ++kk) {
      int k = k4 * 4 + kk;
      float4 wa = *(const float4*)&Ws[k * F + j0];
      float4 wb = *(const float4*)&Ws[k * F + j0 + 4];
#pragma unroll
      for (int u = 0; u < 8; ++u) {
        float xs = (kk == 0) ? xv[u].x : (kk == 1) ? xv[u].y : (kk == 2) ? xv[u].z : xv[u].w;
        acc[u][0] = fmaf(xs, wa.x, acc[u][0]);
        acc[u][1] = fmaf(xs, wa.y, acc[u][1]);
        acc[u][2] = fmaf(xs, wa.z, acc[u][2]);
        acc[u][3] = fmaf(xs, wa.w, acc[u][3]);
        acc[u][4] = fmaf(xs, wb.x, acc[u][4]);
        acc[u][5] = fmaf(xs, wb.y, acc[u][5]);
        acc[u][6] = fmaf(xs, wb.z, acc[u][6]);
        acc[u][7] = fmaf(xs, wb.w, acc[u][7]);
      }
    }
  }

#pragma unroll
  for (int u = 0; u < 8; ++u) {
    int r = i0 + u;
    if (r < N) {
      half8 hv;
#pragma unroll
      for (int v = 0; v < 8; ++v) hv[v] = (_Float16)acc[u][v];
      *(half8*)(xwh + (size_t)r * F + j0) = hv;
    }
  }
}

// ------------- fused gather + ReLU + Linear(F,1), fp16 rows -------------
// one wave per node; quarter-wave (16 lanes) per edge, 4 edges in flight.
// lane c in 0..15 owns features 8c..8c+7 (one 16B half8).
__global__ __launch_bounds__(256) void gather_out(
    const uint2* __restrict__ pairs, const int* __restrict__ offs,
    const float* __restrict__ dinv, const half8* __restrict__ xwv,
    const float* __restrict__ linw, const float* __restrict__ linb,
    float* __restrict__ out, int N) {
  int wave = threadIdx.x >> 6;
  int lane = threadIdx.x & 63;
  int node = blockIdx.x * 4 + wave;
  if (node >= N) return;
  int c = lane & 15;
  int q = lane >> 4;

  float acc[8];
#pragma unroll
  for (int j = 0; j < 8; ++j) acc[j] = 0.f;

  if (q == 0) {  // self-loop, counted once
    float d = dinv[node];
    float s = d * d;
    half8 xv = xwv[(size_t)node * 16 + c];
#pragma unroll
    for (int j = 0; j < 8; ++j) acc[j] = s * (float)xv[j];
  }

  int start = offs[node], end = offs[node + 1];
  int it = start + q;
  for (; it + 4 < end; it += 8) {  // 2 edges per quarter-wave in flight
    uint2 p0 = pairs[it];
    uint2 p1 = pairs[it + 4];
    half8 x0 = xwv[(size_t)p0.x * 16 + c];
    half8 x1 = xwv[(size_t)p1.x * 16 + c];
    float n0 = __uint_as_float(p0.y);
    float n1 = __uint_as_float(p1.y);
#pragma unroll
    for (int j = 0; j < 8; ++j) acc[j] = fmaf(n0, (float)x0[j], acc[j]);
#pragma unroll
    for (int j = 0; j < 8; ++j) acc[j] = fmaf(n1, (float)x1[j], acc[j]);
  }
  if (it < end) {
    uint2 p0 = pairs[it];
    half8 x0 = xwv[(size_t)p0.x * 16 + c];
    float n0 = __uint_as_float(p0.y);
#pragma unroll
    for (int j = 0; j < 8; ++j) acc[j] = fmaf(n0, (float)x0[j], acc[j]);
  }

  // combine the four quarters
#pragma unroll
  for (int j = 0; j < 8; ++j) {
    acc[j] += __shfl_xor(acc[j], 16);
    acc[j] += __shfl_xor(acc[j], 32);
  }

  // ReLU + dot with lin_w
  const float4* lw4 = (const float4*)linw;
  float4 la = lw4[c * 2];
  float4 lb = lw4[c * 2 + 1];
  float p = fmaxf(acc[0], 0.f) * la.x + fmaxf(acc[1], 0.f) * la.y +
            fmaxf(acc[2], 0.f) * la.z + fmaxf(acc[3], 0.f) * la.w +
            fmaxf(acc[4], 0.f) * lb.x + fmaxf(acc[5], 0.f) * lb.y +
            fmaxf(acc[6], 0.f) * lb.z + fmaxf(acc[7], 0.f) * lb.w;
#pragma unroll
  for (int m = 8; m; m >>= 1) p += __shfl_xor(p, m);

  if (lane == 0) out[node] = p + linb[0];
}

extern "C" void kernel_launch(void* const* d_in, const int* in_sizes, int n_in,
                              void* d_out, int out_size, void* d_ws, size_t ws_size,
                              hipStream_t stream) {
  const float* x    = (const float*)d_in[0];
  const int*   ei   = (const int*)d_in[1];
  const float* ew   = (const float*)d_in[2];
  const float* W0   = (const float*)d_in[3];
  const float* wih  = (const float*)d_in[4];
  const float* whh  = (const float*)d_in[5];
  const float* bih  = (const float*)d_in[6];
  const float* bhh  = (const float*)d_in[7];
  const float* linw = (const float*)d_in[8];
  const float* linb = (const float*)d_in[9];

  int N = in_sizes[0] / F;
  int E = in_sizes[2];
  const int* row = ei;
  const int* col = ei + E;

  char* p = (char*)d_ws;
  auto alloc = [&](size_t bytes) {
    char* q = p;
    p += (bytes + 255) & ~(size_t)255;
    return q;
  };
  float*              W      = (float*)alloc((size_t)F * F * 4);
  unsigned long long* packed = (unsigned long long*)alloc((size_t)N * 8);
  unsigned*           rank   = (unsigned*)alloc((size_t)E * 4);
  float*              dinv   = (float*)alloc((size_t)N * 4);
  int*                offs   = (int*)alloc(((size_t)N + 1) * 4);
  int*                bsum   = (int*)alloc(4096);
  int*                bscan  = (int*)alloc(4096);
  uint2*              pairs  = (uint2*)alloc((size_t)E * 8);
  _Float16*           xwh    = (_Float16*)alloc((size_t)N * F * 2);

  hipMemsetAsync(packed, 0, (size_t)N * 8, stream);

  gru_evolve<<<F, F, 0, stream>>>(W0, wih, whh, bih, bhh, W);
  hist_packed<<<(E + 255) / 256, 256, 0, stream>>>(col, ew, packed, rank, E);

  int NB = (N + 1023) / 1024;
  scan_block<<<NB, 1024, 0, stream>>>(packed, offs, bsum, N);
  scan_sums<<<1, 64, 0, stream>>>(bsum, bscan, NB, offs, N);
  finalize_kernel<<<(N + 255) / 256, 256, 0, stream>>>(offs, bscan, packed, dinv, N);

  fill_kernel<<<(E + 255) / 256, 256, 0, stream>>>(row, col, ew, rank, offs, dinv, pairs, E);
  gemm_xw<<<(N + 127) / 128, 256, 0, stream>>>(x, W, xwh, N);
  gather_out<<<(N + 3) / 4, 256, 0, stream>>>(pairs, offs, dinv, (const half8*)xwh,
                                              linw, linb, (float*)d_out, N);
}